// Round 1
// baseline (239.385 us; speedup 1.0000x reference)
//
#include <hip/hip_runtime.h>
#include <hip/hip_bf16.h>

#define S 512
#define KEEP 64
#define SPARSITY 0.125f
#define SLOPE 5.0f

// One block per batch row b. 512 threads, one per frequency line s.
// Computes pmask (rescaled sigmoid), score = pmask - thresh, then exact
// top-64 selection via rank counting (ties broken by lower index, matching
// jax.lax.top_k). Writes binary mask as float [B, S].
__global__ __launch_bounds__(512) void loupe_mask_kernel(
    const float* __restrict__ weight,
    const float* __restrict__ thresh,
    float* __restrict__ mask) {
    __shared__ float red[S];
    __shared__ float sc[S];

    const int b = blockIdx.x;
    const int s = threadIdx.x;

    // Numerically-stable sigmoid, matching jax.nn.sigmoid's formulation.
    const float z = SLOPE * weight[s];
    const float e = expf(-fabsf(z));
    const float x = (z >= 0.0f) ? (1.0f / (1.0f + e)) : (e / (1.0f + e));

    // Block-wide mean of x (tree reduce in LDS).
    red[s] = x;
    __syncthreads();
    #pragma unroll
    for (int off = S / 2; off > 0; off >>= 1) {
        if (s < off) red[s] += red[s + off];
        __syncthreads();
    }
    const float xbar = red[0] * (1.0f / (float)S);

    // rescale_prob: scalar condition -> uniform branch.
    float pm;
    if (xbar > SPARSITY) {
        pm = x * SPARSITY / xbar;
    } else {
        pm = 1.0f - (1.0f - x) * (1.0f - SPARSITY) / (1.0f - xbar);
    }

    const float score = pm - thresh[b * S + s];
    sc[s] = score;
    __syncthreads();

    // Exact rank: number of elements strictly greater, plus equal-valued
    // elements at a lower index (top_k tie-break = lowest index first).
    int rank = 0;
    #pragma unroll 8
    for (int j = 0; j < S; ++j) {
        const float o = sc[j];
        rank += (o > score) || (o == score && j < s);
    }
    mask[b * S + s] = (rank < KEEP) ? 1.0f : 0.0f;
}

// Streaming multiply: out[b,c,h,s] = example[b,c,h,s] * mask[b,s].
// float4 vectorized; per batch there are (C*H*S/4) = 8*512*128 = 2^19 float4s.
__global__ __launch_bounds__(256) void loupe_apply_kernel(
    const float4* __restrict__ ex,
    const float4* __restrict__ mask4,   // [B][S/4]
    float4* __restrict__ out,
    int total4) {
    const int stride = gridDim.x * blockDim.x;
    for (int i = blockIdx.x * blockDim.x + threadIdx.x; i < total4; i += stride) {
        const int b  = i >> 19;        // / (8*512*128)
        const int s4 = i & 127;        // % (512/4)
        const float4 m = mask4[b * 128 + s4];
        const float4 e = ex[i];
        float4 o;
        o.x = e.x * m.x;
        o.y = e.y * m.y;
        o.z = e.z * m.z;
        o.w = e.w * m.w;
        out[i] = o;
    }
}

extern "C" void kernel_launch(void* const* d_in, const int* in_sizes, int n_in,
                              void* d_out, int out_size, void* d_ws, size_t ws_size,
                              hipStream_t stream) {
    const float* example = (const float*)d_in[0];   // [64, 8, 512, 512]
    const float* weight  = (const float*)d_in[1];   // [512]
    const float* thresh  = (const float*)d_in[2];   // [64, 512]
    float* out  = (float*)d_out;
    float* mask = (float*)d_ws;                     // [64, 512] floats = 128 KB

    const int B = in_sizes[2] / S;                  // 64

    loupe_mask_kernel<<<B, S, 0, stream>>>(weight, thresh, mask);

    const int total4 = out_size / 4;                // 16,777,216 float4s
    const int blocks = 4096;
    loupe_apply_kernel<<<blocks, 256, 0, stream>>>(
        (const float4*)example, (const float4*)mask, (float4*)out, total4);
}

// Round 2
// 229.682 us; speedup vs baseline: 1.0422x; 1.0422x over previous
//
#include <hip/hip_runtime.h>
#include <hip/hip_bf16.h>

#define S 512
#define KEEP 64
#define SPARSITY 0.125f
#define SLOPE 5.0f

// Geometry: example is [B=64, C=8, H=512, S=512] f32.
// Per batch: C*H = 4096 rows of S floats; in float4 units: 4096 rows x 128.
#define ROW4 128            // float4 per row (S/4)
#define ROWS_PER_BATCH 4096 // C*H
#define BLOCKS_PER_BATCH 32
#define ROWS_PER_BLOCK 128  // ROWS_PER_BATCH / BLOCKS_PER_BATCH
#define BATCH4 524288       // ROWS_PER_BATCH * ROW4

// One block per batch row b. 512 threads, one per frequency line s.
// Exact top-64 via rank counting (ties -> lowest index, matching lax.top_k).
__global__ __launch_bounds__(512) void loupe_mask_kernel(
    const float* __restrict__ weight,
    const float* __restrict__ thresh,
    float* __restrict__ mask) {
    __shared__ float red[S];
    __shared__ float sc[S];

    const int b = blockIdx.x;
    const int s = threadIdx.x;

    // Numerically-stable sigmoid, matching jax.nn.sigmoid.
    const float z = SLOPE * weight[s];
    const float e = expf(-fabsf(z));
    const float x = (z >= 0.0f) ? (1.0f / (1.0f + e)) : (e / (1.0f + e));

    // Block-wide mean of x.
    red[s] = x;
    __syncthreads();
    #pragma unroll
    for (int off = S / 2; off > 0; off >>= 1) {
        if (s < off) red[s] += red[s + off];
        __syncthreads();
    }
    const float xbar = red[0] * (1.0f / (float)S);

    float pm;
    if (xbar > SPARSITY) {
        pm = x * SPARSITY / xbar;
    } else {
        pm = 1.0f - (1.0f - x) * (1.0f - SPARSITY) / (1.0f - xbar);
    }

    const float score = pm - thresh[b * S + s];
    sc[s] = score;
    __syncthreads();

    int rank = 0;
    #pragma unroll 8
    for (int j = 0; j < S; ++j) {
        const float o = sc[j];
        rank += (o > score) || (o == score && j < s);
    }
    mask[b * S + s] = (rank < KEEP) ? 1.0f : 0.0f;
}

// Streaming multiply with register-resident mask.
// Block (b, chunk): sweeps rows [chunk*128, chunk*128+128) of batch b.
// Thread t: fixed column s4 = t&127, row parity t>>7. Each iteration the
// block covers 2 full rows (256 float4 = 4 KB, contiguous). All loads are
// independent -> unroll 8 gives 8 HBM loads in flight per thread.
__global__ __launch_bounds__(256) void loupe_apply_kernel(
    const float4* __restrict__ ex,
    const float4* __restrict__ mask4,   // [B][ROW4]
    float4* __restrict__ out) {
    const int b     = blockIdx.x >> 5;          // / BLOCKS_PER_BATCH
    const int chunk = blockIdx.x & 31;
    const int t     = threadIdx.x;
    const int s4    = t & 127;
    const int rowo  = t >> 7;                    // 0 or 1

    const float4 m = mask4[b * ROW4 + s4];       // loaded once

    int idx = b * BATCH4 + (chunk * ROWS_PER_BLOCK + rowo) * ROW4 + s4;
    #pragma unroll 8
    for (int k = 0; k < ROWS_PER_BLOCK / 2; ++k) {
        const float4 e = ex[idx];
        float4 o;
        o.x = e.x * m.x;
        o.y = e.y * m.y;
        o.z = e.z * m.z;
        o.w = e.w * m.w;
        out[idx] = o;
        idx += 2 * ROW4;                         // advance 2 rows
    }
}

extern "C" void kernel_launch(void* const* d_in, const int* in_sizes, int n_in,
                              void* d_out, int out_size, void* d_ws, size_t ws_size,
                              hipStream_t stream) {
    const float* example = (const float*)d_in[0];   // [64, 8, 512, 512]
    const float* weight  = (const float*)d_in[1];   // [512]
    const float* thresh  = (const float*)d_in[2];   // [64, 512]
    float* out  = (float*)d_out;
    float* mask = (float*)d_ws;                     // [64, 512] floats = 128 KB

    const int B = in_sizes[2] / S;                  // 64

    loupe_mask_kernel<<<B, S, 0, stream>>>(weight, thresh, mask);

    loupe_apply_kernel<<<B * BLOCKS_PER_BATCH, 256, 0, stream>>>(
        (const float4*)example, (const float4*)mask, (float4*)out);
}

// Round 3
// 207.776 us; speedup vs baseline: 1.1521x; 1.1054x over previous
//
#include <hip/hip_runtime.h>
#include <hip/hip_bf16.h>

#define S 512
#define KEEP 64
#define SPARSITY 0.125f
#define SLOPE 5.0f

// Geometry: example is [B=64, C=8, H=512, S=512] f32.
#define ROW4 128            // float4 per row (S/4)
#define ROWS_PER_BATCH 4096 // C*H
#define BLOCKS_PER_BATCH 32
#define ROWS_PER_BLOCK 128  // ROWS_PER_BATCH / BLOCKS_PER_BATCH
#define BATCH4 524288       // ROWS_PER_BATCH * ROW4

typedef float vf4 __attribute__((ext_vector_type(4)));

// One block per batch row b. 512 threads, one per frequency line s.
// Exact top-64 via rank counting (ties -> lowest index, matching lax.top_k).
__global__ __launch_bounds__(512) void loupe_mask_kernel(
    const float* __restrict__ weight,
    const float* __restrict__ thresh,
    float* __restrict__ mask) {
    __shared__ float red[S];
    __shared__ float sc[S];

    const int b = blockIdx.x;
    const int s = threadIdx.x;

    // Numerically-stable sigmoid, matching jax.nn.sigmoid.
    const float z = SLOPE * weight[s];
    const float e = expf(-fabsf(z));
    const float x = (z >= 0.0f) ? (1.0f / (1.0f + e)) : (e / (1.0f + e));

    red[s] = x;
    __syncthreads();
    #pragma unroll
    for (int off = S / 2; off > 0; off >>= 1) {
        if (s < off) red[s] += red[s + off];
        __syncthreads();
    }
    const float xbar = red[0] * (1.0f / (float)S);

    float pm;
    if (xbar > SPARSITY) {
        pm = x * SPARSITY / xbar;
    } else {
        pm = 1.0f - (1.0f - x) * (1.0f - SPARSITY) / (1.0f - xbar);
    }

    const float score = pm - thresh[b * S + s];
    sc[s] = score;
    __syncthreads();

    int rank = 0;
    #pragma unroll 8
    for (int j = 0; j < S; ++j) {
        const float o = sc[j];
        rank += (o > score) || (o == score && j < s);
    }
    mask[b * S + s] = (rank < KEEP) ? 1.0f : 0.0f;
}

// Streaming multiply, register-resident mask, explicit 8-deep load batching,
// non-temporal loads/stores (streaming data has zero reuse; keep it out of
// L2/L3 so the two 537 MB streams don't fight the caches).
__global__ __launch_bounds__(256) void loupe_apply_kernel(
    const vf4* __restrict__ ex,
    const vf4* __restrict__ mask4,   // [B][ROW4]
    vf4* __restrict__ out) {
    const int b     = blockIdx.x >> 5;          // / BLOCKS_PER_BATCH
    const int chunk = blockIdx.x & 31;
    const int t     = threadIdx.x;
    const int s4    = t & 127;
    const int rowo  = t >> 7;                    // 0 or 1

    const vf4 m = mask4[b * ROW4 + s4];          // loaded once, L2-hit

    const vf4* src = ex  + b * BATCH4 + (chunk * ROWS_PER_BLOCK + rowo) * ROW4 + s4;
    vf4*       dst = out + b * BATCH4 + (chunk * ROWS_PER_BLOCK + rowo) * ROW4 + s4;

    #pragma unroll
    for (int g = 0; g < 8; ++g) {
        vf4 e[8];
        #pragma unroll
        for (int u = 0; u < 8; ++u)
            e[u] = __builtin_nontemporal_load(src + u * 2 * ROW4);
        #pragma unroll
        for (int u = 0; u < 8; ++u)
            __builtin_nontemporal_store(e[u] * m, dst + u * 2 * ROW4);
        src += 16 * ROW4;
        dst += 16 * ROW4;
    }
}

extern "C" void kernel_launch(void* const* d_in, const int* in_sizes, int n_in,
                              void* d_out, int out_size, void* d_ws, size_t ws_size,
                              hipStream_t stream) {
    const float* example = (const float*)d_in[0];   // [64, 8, 512, 512]
    const float* weight  = (const float*)d_in[1];   // [512]
    const float* thresh  = (const float*)d_in[2];   // [64, 512]
    float* out  = (float*)d_out;
    float* mask = (float*)d_ws;                     // [64, 512] floats = 128 KB

    const int B = in_sizes[2] / S;                  // 64

    loupe_mask_kernel<<<B, S, 0, stream>>>(weight, thresh, mask);

    loupe_apply_kernel<<<B * BLOCKS_PER_BATCH, 256, 0, stream>>>(
        (const vf4*)example, (const vf4*)mask, (vf4*)out);
}